// Round 1
// baseline (1850.223 us; speedup 1.0000x reference)
//
#include <hip/hip_runtime.h>
#include <hip/hip_bf16.h>

#define N_NODES 100000
#define N_EDGES 625000
#define D 128
#define N_LAYERS 10
#define SCAN_BLOCKS 98   // ceil(100000/1024)

// ---------------- CSR build (once per call) ----------------

__global__ void hist_kernel(const int* __restrict__ dst, int* __restrict__ deg) {
    int e = blockIdx.x * blockDim.x + threadIdx.x;
    if (e < N_EDGES) atomicAdd(&deg[dst[e]], 1);
}

__global__ void scanA_kernel(const int* __restrict__ deg, int* __restrict__ offsets,
                             int* __restrict__ blockSums) {
    __shared__ int s[1024];
    int tid = threadIdx.x;
    int i = blockIdx.x * 1024 + tid;
    int v = (i < N_NODES) ? deg[i] : 0;
    s[tid] = v;
    __syncthreads();
    for (int d = 1; d < 1024; d <<= 1) {
        int t = (tid >= d) ? s[tid - d] : 0;
        __syncthreads();
        s[tid] += t;
        __syncthreads();
    }
    if (i < N_NODES) offsets[i] = s[tid] - v;   // exclusive
    if (tid == 1023) blockSums[blockIdx.x] = s[1023];
}

__global__ void scanB_kernel(const int* __restrict__ blockSums, int* __restrict__ blockOffsets) {
    __shared__ int s[128];
    int tid = threadIdx.x;
    int v = (tid < SCAN_BLOCKS) ? blockSums[tid] : 0;
    s[tid] = v;
    __syncthreads();
    for (int d = 1; d < 128; d <<= 1) {
        int t = (tid >= d) ? s[tid - d] : 0;
        __syncthreads();
        s[tid] += t;
        __syncthreads();
    }
    blockOffsets[tid] = s[tid] - v;             // exclusive
}

__global__ void scanC_kernel(int* __restrict__ offsets, const int* __restrict__ blockOffsets) {
    int i = blockIdx.x * 1024 + threadIdx.x;
    if (i < N_NODES) offsets[i] += blockOffsets[blockIdx.x];
}

__global__ void invdeg_kernel(const int* __restrict__ deg, float* __restrict__ invdeg) {
    int i = blockIdx.x * blockDim.x + threadIdx.x;
    if (i < N_NODES) {
        int d = deg[i];
        invdeg[i] = 1.0f / (float)(d > 0 ? d : 1);
    }
}

__global__ void scatter_kernel(const int* __restrict__ src, const int* __restrict__ dst,
                               const int* __restrict__ offsets, int* __restrict__ fill,
                               int* __restrict__ srcSorted) {
    int e = blockIdx.x * blockDim.x + threadIdx.x;
    if (e < N_EDGES) {
        int d_ = dst[e];
        int pos = offsets[d_] + atomicAdd(&fill[d_], 1);
        srcSorted[pos] = src[e];
    }
}

// ---------------- per-layer: mean aggregation (gather via CSR) ----------------
// one wave per node; lane handles 2 columns via float2 (64*8B = 512B/row, coalesced)
__global__ __launch_bounds__(256) void agg_kernel(
        const float* __restrict__ xin, const int* __restrict__ srcSorted,
        const int* __restrict__ offsets, const int* __restrict__ deg,
        const float* __restrict__ invdeg, float* __restrict__ agg) {
    int node = blockIdx.x * 4 + (threadIdx.x >> 6);
    int lane = threadIdx.x & 63;
    if (node >= N_NODES) return;
    int off = offsets[node];
    int cnt = deg[node];
    const float2* x2 = (const float2*)xin;
    float sx = 0.f, sy = 0.f;
    for (int k = off; k < off + cnt; ++k) {
        int s = srcSorted[k];
        float2 v = x2[(size_t)s * 64 + lane];
        sx += v.x; sy += v.y;
    }
    float inv = invdeg[node];
    float2 o; o.x = sx * inv; o.y = sy * inv;
    ((float2*)agg)[(size_t)node * 64 + lane] = o;
}

// ---------------- per-layer: out = agg@Wl + x@Wr + b (+relu), in-place safe ----------------
// block = 256 threads, tile = 64 rows x 128 cols, thread = 8 rows x 4 cols
__global__ __launch_bounds__(256) void gemm_kernel(
        const float* __restrict__ A, const float* __restrict__ X,
        const float* __restrict__ Wl, const float* __restrict__ Wr,
        const float* __restrict__ bias, float* __restrict__ out, int relu) {
    __shared__ float As[32][68];    // [k][row], +4 pad keeps b128 alignment, breaks worst conflicts
    __shared__ float Ws[32][128];   // [k][col]
    int tid = threadIdx.x;
    int cg = tid & 31;              // cols 4*cg .. 4*cg+3
    int rg = tid >> 5;              // rows 8*rg .. 8*rg+7
    int row0 = blockIdx.x * 64;

    float acc[8][4];
#pragma unroll
    for (int r = 0; r < 8; ++r)
#pragma unroll
        for (int c = 0; c < 4; ++c) acc[r][c] = 0.f;

    int lr = tid >> 3;              // 0..31 (row within half-tile for A-load)
    int kq = tid & 7;               // 0..7  (float4 within 32-wide k chunk)

    for (int phase = 0; phase < 2; ++phase) {
        const float* Ap = phase ? X : A;
        const float* Wp = phase ? Wr : Wl;
#pragma unroll 1
        for (int kc = 0; kc < 4; ++kc) {
            int k0 = kc * 32;
            // stage A chunk (64 rows x 32 k), transposed into As[k][row]
#pragma unroll
            for (int p = 0; p < 2; ++p) {
                int rr = lr + 32 * p;
                int grow = row0 + rr;
                float4 v = make_float4(0.f, 0.f, 0.f, 0.f);
                if (grow < N_NODES)
                    v = *(const float4*)&Ap[(size_t)grow * D + k0 + 4 * kq];
                As[4 * kq + 0][rr] = v.x;
                As[4 * kq + 1][rr] = v.y;
                As[4 * kq + 2][rr] = v.z;
                As[4 * kq + 3][rr] = v.w;
            }
            // stage W chunk (32 k x 128 cols)
#pragma unroll
            for (int q = 0; q < 4; ++q) {
                int lin = tid + 256 * q;          // float4 index, 0..1023
                int kk = lin >> 5;
                int c4 = lin & 31;
                *(float4*)&Ws[kk][4 * c4] = *(const float4*)&Wp[(size_t)(k0 + kk) * D + 4 * c4];
            }
            __syncthreads();
#pragma unroll
            for (int kk = 0; kk < 32; ++kk) {
                float4 a0 = *(const float4*)&As[kk][8 * rg];
                float4 a1 = *(const float4*)&As[kk][8 * rg + 4];
                float4 wv = *(const float4*)&Ws[kk][4 * cg];
                float ar[8] = {a0.x, a0.y, a0.z, a0.w, a1.x, a1.y, a1.z, a1.w};
                float wc[4] = {wv.x, wv.y, wv.z, wv.w};
#pragma unroll
                for (int r = 0; r < 8; ++r)
#pragma unroll
                    for (int c = 0; c < 4; ++c)
                        acc[r][c] += ar[r] * wc[c];
            }
            __syncthreads();
        }
    }

    float4 bv = *(const float4*)&bias[4 * cg];
    float bb[4] = {bv.x, bv.y, bv.z, bv.w};
#pragma unroll
    for (int r = 0; r < 8; ++r) {
        int grow = row0 + 8 * rg + r;
        if (grow < N_NODES) {
            float4 o;
            float v0 = acc[r][0] + bb[0];
            float v1 = acc[r][1] + bb[1];
            float v2 = acc[r][2] + bb[2];
            float v3 = acc[r][3] + bb[3];
            if (relu) {
                v0 = fmaxf(v0, 0.f); v1 = fmaxf(v1, 0.f);
                v2 = fmaxf(v2, 0.f); v3 = fmaxf(v3, 0.f);
            }
            o.x = v0; o.y = v1; o.z = v2; o.w = v3;
            *(float4*)&out[(size_t)grow * D + 4 * cg] = o;
        }
    }
}

extern "C" void kernel_launch(void* const* d_in, const int* in_sizes, int n_in,
                              void* d_out, int out_size, void* d_ws, size_t ws_size,
                              hipStream_t stream) {
    const float* x  = (const float*)d_in[0];
    const float* Wl = (const float*)d_in[1];
    const float* Wr = (const float*)d_in[2];
    const float* b  = (const float*)d_in[3];
    const int*   ei = (const int*)d_in[4];
    const int* src = ei;
    const int* dst = ei + N_EDGES;
    float* out = (float*)d_out;

    char* w = (char*)d_ws;
    auto alloc = [&](size_t bytes) -> char* {
        char* p = w;
        w += (bytes + 255) & ~(size_t)255;
        return p;
    };
    float* agg       = (float*)alloc((size_t)N_NODES * D * 4);
    float* xbuf      = (float*)alloc((size_t)N_NODES * D * 4);
    int*   deg       = (int*)alloc((size_t)N_NODES * 4);
    int*   offsets   = (int*)alloc((size_t)N_NODES * 4);
    int*   fill      = (int*)alloc((size_t)N_NODES * 4);
    int*   srcSorted = (int*)alloc((size_t)N_EDGES * 4);
    int*   blockSums = (int*)alloc(128 * 4);
    int*   blockOffs = (int*)alloc(128 * 4);
    float* invdeg    = (float*)alloc((size_t)N_NODES * 4);

    hipMemsetAsync(deg, 0, (size_t)N_NODES * 4, stream);
    hipMemsetAsync(fill, 0, (size_t)N_NODES * 4, stream);

    hist_kernel<<<(N_EDGES + 255) / 256, 256, 0, stream>>>(dst, deg);
    scanA_kernel<<<SCAN_BLOCKS, 1024, 0, stream>>>(deg, offsets, blockSums);
    scanB_kernel<<<1, 128, 0, stream>>>(blockSums, blockOffs);
    scanC_kernel<<<SCAN_BLOCKS, 1024, 0, stream>>>(offsets, blockOffs);
    invdeg_kernel<<<(N_NODES + 255) / 256, 256, 0, stream>>>(deg, invdeg);
    scatter_kernel<<<(N_EDGES + 255) / 256, 256, 0, stream>>>(src, dst, offsets, fill, srcSorted);

    const float* cur = x;
    for (int L = 0; L < N_LAYERS; ++L) {
        agg_kernel<<<(N_NODES + 3) / 4, 256, 0, stream>>>(cur, srcSorted, offsets, deg, invdeg, agg);
        float* dsto = (L == N_LAYERS - 1) ? out : xbuf;
        gemm_kernel<<<(N_NODES + 63) / 64, 256, 0, stream>>>(
            agg, cur, Wl + (size_t)L * D * D, Wr + (size_t)L * D * D, b + (size_t)L * D,
            dsto, (L < N_LAYERS - 1) ? 1 : 0);
        cur = dsto;
    }
}

// Round 2
// 1249.102 us; speedup vs baseline: 1.4812x; 1.4812x over previous
//
#include <hip/hip_runtime.h>
#include <hip/hip_bf16.h>

#define N_NODES 100000
#define N_EDGES 625000
#define D 128
#define N_LAYERS 10
#define SCAN_BLOCKS 98   // ceil(100000/1024)

typedef __attribute__((ext_vector_type(8))) short bf16x8;
typedef __attribute__((ext_vector_type(4))) float floatx4;

static __device__ __forceinline__ ushort f2bf(float f) {
    uint u = __float_as_uint(f);
    u += 0x7fff + ((u >> 16) & 1);   // round-to-nearest-even
    return (ushort)(u >> 16);
}
static __device__ __forceinline__ float bf2f(ushort h) {
    return __uint_as_float(((uint)h) << 16);
}

// ---------------- CSR build (once per call) ----------------

__global__ void hist_kernel(const int* __restrict__ dst, int* __restrict__ deg) {
    int e = blockIdx.x * blockDim.x + threadIdx.x;
    if (e < N_EDGES) atomicAdd(&deg[dst[e]], 1);
}

__global__ void scanA_kernel(const int* __restrict__ deg, int* __restrict__ offsets,
                             int* __restrict__ blockSums) {
    __shared__ int s[1024];
    int tid = threadIdx.x;
    int i = blockIdx.x * 1024 + tid;
    int v = (i < N_NODES) ? deg[i] : 0;
    s[tid] = v;
    __syncthreads();
    for (int d = 1; d < 1024; d <<= 1) {
        int t = (tid >= d) ? s[tid - d] : 0;
        __syncthreads();
        s[tid] += t;
        __syncthreads();
    }
    if (i < N_NODES) offsets[i] = s[tid] - v;   // exclusive
    if (tid == 1023) blockSums[blockIdx.x] = s[1023];
}

__global__ void scanB_kernel(const int* __restrict__ blockSums, int* __restrict__ blockOffsets) {
    __shared__ int s[128];
    int tid = threadIdx.x;
    int v = (tid < SCAN_BLOCKS) ? blockSums[tid] : 0;
    s[tid] = v;
    __syncthreads();
    for (int d = 1; d < 128; d <<= 1) {
        int t = (tid >= d) ? s[tid - d] : 0;
        __syncthreads();
        s[tid] += t;
        __syncthreads();
    }
    blockOffsets[tid] = s[tid] - v;             // exclusive
}

__global__ void scanC_kernel(int* __restrict__ offsets, const int* __restrict__ blockOffsets) {
    int i = blockIdx.x * 1024 + threadIdx.x;
    if (i < N_NODES) offsets[i] += blockOffsets[blockIdx.x];
}

__global__ void invdeg_kernel(const int* __restrict__ deg, float* __restrict__ invdeg) {
    int i = blockIdx.x * blockDim.x + threadIdx.x;
    if (i < N_NODES) {
        int d = deg[i];
        invdeg[i] = 1.0f / (float)(d > 0 ? d : 1);
    }
}

__global__ void scatter_kernel(const int* __restrict__ src, const int* __restrict__ dst,
                               const int* __restrict__ offsets, int* __restrict__ fill,
                               int* __restrict__ srcSorted) {
    int e = blockIdx.x * blockDim.x + threadIdx.x;
    if (e < N_EDGES) {
        int d_ = dst[e];
        int pos = offsets[d_] + atomicAdd(&fill[d_], 1);
        srcSorted[pos] = src[e];
    }
}

// ---------------- W hi/lo split into B-fragment layout (once per call) ----------------
// layout: (((layer*4 + s)*16 + ntile)*64 + lane)*8, element j: k = s*32+(lane>>4)*8+j,
// n = ntile*16 + (lane&15); n<128 -> Wl, else Wr (col n-128)
__global__ void wsplit_kernel(const float* __restrict__ Wl, const float* __restrict__ Wr,
                              ushort* __restrict__ Whi, ushort* __restrict__ Wlo) {
    int t = blockIdx.x * blockDim.x + threadIdx.x;
    if (t >= N_LAYERS * 4 * 16 * 64) return;
    int lane  = t & 63;
    int ntile = (t >> 6) & 15;
    int s     = (t >> 10) & 3;
    int layer = t >> 12;
    int n = ntile * 16 + (lane & 15);
    int kbase = s * 32 + (lane >> 4) * 8;
    const float* W = (n < 128) ? (Wl + (size_t)layer * D * D + n)
                               : (Wr + (size_t)layer * D * D + (n - 128));
    size_t off = (size_t)t * 8;
#pragma unroll
    for (int j = 0; j < 8; ++j) {
        float w = W[(size_t)(kbase + j) * D];
        ushort hh = f2bf(w);
        Whi[off + j] = hh;
        Wlo[off + j] = f2bf(w - bf2f(hh));
    }
}

// ---------------- per layer: h = x@Wl (bf16), z = x@Wr + b (fp32, in-place-safe over x) ----
// block 256 = 4 waves; M-tile 16 rows, K=128, N=256 (waves 0-1 -> h cols, 2-3 -> z cols)
__global__ __launch_bounds__(256) void gemm_hz(
        const float* __restrict__ X, const ushort* __restrict__ Whi,
        const ushort* __restrict__ Wlo, const float* __restrict__ bias,
        ushort* __restrict__ h, float* __restrict__ z) {
    __shared__ ushort Ahi[4 * 64 * 8];   // [s][lane^ (s<<2)][8]  (4 KB)
    __shared__ ushort Alo[4 * 64 * 8];

    int tid  = threadIdx.x;
    int lane = tid & 63;
    int wave = tid >> 6;

    // staging indices: thread (r, t0) loads A[row0+r][t0*8 .. t0*8+7]
    int r    = tid >> 4;       // 0..15
    int t0   = tid & 15;       // 0..15 (8-float chunk)
    int s_st = t0 >> 2;
    int q_st = t0 & 3;
    int lanep = (q_st << 4) | r;
    int stIdx = (s_st * 64 + (lanep ^ (s_st << 2))) * 8;

    int q  = lane >> 4;        // D-frag quad
    int cc = lane & 15;        // D-frag col-in-tile

    float bsc[4] = {0.f, 0.f, 0.f, 0.f};
    if (wave >= 2) {
#pragma unroll
        for (int nt = 0; nt < 4; ++nt)
            bsc[nt] = bias[((wave * 4 + nt) - 8) * 16 + cc];
    }

    for (int mt = blockIdx.x; mt < N_NODES / 16; mt += gridDim.x) {
        int row0 = mt * 16;
        // ---- stage A tile, split hi/lo ----
        const float* xp = X + (size_t)(row0 + r) * D + t0 * 8;
        float4 v0 = *(const float4*)xp;
        float4 v1 = *(const float4*)(xp + 4);
        float a[8] = {v0.x, v0.y, v0.z, v0.w, v1.x, v1.y, v1.z, v1.w};
        ushort hi8[8], lo8[8];
#pragma unroll
        for (int j = 0; j < 8; ++j) {
            ushort hh = f2bf(a[j]);
            hi8[j] = hh;
            lo8[j] = f2bf(a[j] - bf2f(hh));
        }
        *(bf16x8*)&Ahi[stIdx] = *(bf16x8*)hi8;
        *(bf16x8*)&Alo[stIdx] = *(bf16x8*)lo8;
        __syncthreads();

        // ---- MFMA: 3-pass split ----
        floatx4 acc[4];
#pragma unroll
        for (int nt = 0; nt < 4; ++nt) acc[nt] = (floatx4){0.f, 0.f, 0.f, 0.f};
#pragma unroll
        for (int s = 0; s < 4; ++s) {
            int aIdx = (s * 64 + (lane ^ (s << 2))) * 8;
            bf16x8 ah = *(const bf16x8*)&Ahi[aIdx];
            bf16x8 al = *(const bf16x8*)&Alo[aIdx];
#pragma unroll
            for (int nt = 0; nt < 4; ++nt) {
                int ntile = wave * 4 + nt;
                size_t wo = ((size_t)(s * 16 + ntile) * 64 + lane) * 8;
                bf16x8 wh = *(const bf16x8*)&Whi[wo];
                bf16x8 wl = *(const bf16x8*)&Wlo[wo];
                acc[nt] = __builtin_amdgcn_mfma_f32_16x16x32_bf16(ah, wh, acc[nt], 0, 0, 0);
                acc[nt] = __builtin_amdgcn_mfma_f32_16x16x32_bf16(al, wh, acc[nt], 0, 0, 0);
                acc[nt] = __builtin_amdgcn_mfma_f32_16x16x32_bf16(ah, wl, acc[nt], 0, 0, 0);
            }
        }
        __syncthreads();   // LDS reads done before next iter's staging

        // ---- epilogue: D row = q*4+rr, col = ntile*16+cc ----
        if (wave < 2) {
#pragma unroll
            for (int nt = 0; nt < 4; ++nt) {
                int col = (wave * 4 + nt) * 16 + cc;
#pragma unroll
                for (int rr = 0; rr < 4; ++rr) {
                    int row = row0 + q * 4 + rr;
                    h[(size_t)row * D + col] = f2bf(acc[nt][rr]);
                }
            }
        } else {
#pragma unroll
            for (int nt = 0; nt < 4; ++nt) {
                int col = ((wave * 4 + nt) - 8) * 16 + cc;
#pragma unroll
                for (int rr = 0; rr < 4; ++rr) {
                    int row = row0 + q * 4 + rr;
                    z[(size_t)row * D + col] = acc[nt][rr] + bsc[nt];
                }
            }
        }
    }
}

// ---------------- per layer: out = relu?(mean_agg(h) + z), in-place-safe over z ----------
// wave per node; lane reads 2 bf16 cols packed in a uint (256B/row, coalesced)
__global__ __launch_bounds__(256) void agg_add_kernel(
        const ushort* __restrict__ h, const int* __restrict__ srcSorted,
        const int* __restrict__ offsets, const int* __restrict__ deg,
        const float* __restrict__ invdeg, const float* __restrict__ zin,
        float* __restrict__ out, int relu) {
    int node = blockIdx.x * 4 + (threadIdx.x >> 6);
    int lane = threadIdx.x & 63;
    int off = offsets[node];
    int cnt = deg[node];
    const uint* h2 = (const uint*)h;
    float sx = 0.f, sy = 0.f;
    for (int k = off; k < off + cnt; ++k) {
        int s = srcSorted[k];
        uint u = h2[(size_t)s * 64 + lane];
        sx += __uint_as_float(u << 16);
        sy += __uint_as_float(u & 0xffff0000u);
    }
    float inv = invdeg[node];
    float2 zv = ((const float2*)zin)[(size_t)node * 64 + lane];
    float ox = sx * inv + zv.x;
    float oy = sy * inv + zv.y;
    if (relu) { ox = fmaxf(ox, 0.f); oy = fmaxf(oy, 0.f); }
    float2 o; o.x = ox; o.y = oy;
    ((float2*)out)[(size_t)node * 64 + lane] = o;
}

extern "C" void kernel_launch(void* const* d_in, const int* in_sizes, int n_in,
                              void* d_out, int out_size, void* d_ws, size_t ws_size,
                              hipStream_t stream) {
    const float* x  = (const float*)d_in[0];
    const float* Wl = (const float*)d_in[1];
    const float* Wr = (const float*)d_in[2];
    const float* b  = (const float*)d_in[3];
    const int*   ei = (const int*)d_in[4];
    const int* src = ei;
    const int* dst = ei + N_EDGES;
    float* out = (float*)d_out;

    char* w = (char*)d_ws;
    auto alloc = [&](size_t bytes) -> char* {
        char* p = w;
        w += (bytes + 255) & ~(size_t)255;
        return p;
    };
    float*  zx        = (float*)alloc((size_t)N_NODES * D * 4);   // z buffer == activation buffer
    ushort* hbuf      = (ushort*)alloc((size_t)N_NODES * D * 2);
    ushort* Whi       = (ushort*)alloc((size_t)N_LAYERS * 4 * 16 * 64 * 8 * 2);
    ushort* Wlo       = (ushort*)alloc((size_t)N_LAYERS * 4 * 16 * 64 * 8 * 2);
    int*    deg       = (int*)alloc((size_t)N_NODES * 4);
    int*    offsets   = (int*)alloc((size_t)N_NODES * 4);
    int*    fill      = (int*)alloc((size_t)N_NODES * 4);
    int*    srcSorted = (int*)alloc((size_t)N_EDGES * 4);
    int*    blockSums = (int*)alloc(128 * 4);
    int*    blockOffs = (int*)alloc(128 * 4);
    float*  invdeg    = (float*)alloc((size_t)N_NODES * 4);

    hipMemsetAsync(deg, 0, (size_t)N_NODES * 4, stream);
    hipMemsetAsync(fill, 0, (size_t)N_NODES * 4, stream);

    hist_kernel<<<(N_EDGES + 255) / 256, 256, 0, stream>>>(dst, deg);
    scanA_kernel<<<SCAN_BLOCKS, 1024, 0, stream>>>(deg, offsets, blockSums);
    scanB_kernel<<<1, 128, 0, stream>>>(blockSums, blockOffs);
    scanC_kernel<<<SCAN_BLOCKS, 1024, 0, stream>>>(offsets, blockOffs);
    invdeg_kernel<<<(N_NODES + 255) / 256, 256, 0, stream>>>(deg, invdeg);
    scatter_kernel<<<(N_EDGES + 255) / 256, 256, 0, stream>>>(src, dst, offsets, fill, srcSorted);
    wsplit_kernel<<<(N_LAYERS * 4 * 16 * 64 + 255) / 256, 256, 0, stream>>>(Wl, Wr, Whi, Wlo);

    const float* cur = x;
    for (int L = 0; L < N_LAYERS; ++L) {
        size_t woff = (size_t)L * 4 * 16 * 64 * 8;
        gemm_hz<<<1568, 256, 0, stream>>>(cur, Whi + woff, Wlo + woff,
                                          b + (size_t)L * D, hbuf, zx);
        float* o = (L == N_LAYERS - 1) ? out : zx;
        agg_add_kernel<<<N_NODES / 4, 256, 0, stream>>>(
            hbuf, srcSorted, offsets, deg, invdeg, zx, o, (L < N_LAYERS - 1) ? 1 : 0);
        cur = o;
    }
}